// Round 1
// baseline (6073.666 us; speedup 1.0000x reference)
//
#include <hip/hip_runtime.h>
#include <cstdint>
#include <cstddef>

#define B_ROWS 4096
#define D_SAE  16384
#define KD     2304    // L*D_IN contraction length
#define ROWLEN 4608    // T*L*D_IN decode row length
#define TOPK   64

// ---------------------------------------------------------------------------
// Encode GEMM: pre[b,s] = sum_ld (x[b,0,ld] + x[b,1,ld]) * W_enc[ld,s] + b_enc[s]
// A = t-summed x (4096 x 2304, staged on the fly), B = W_enc (2304 x 16384 row-major)
// 128x128 tile, BK=8, 256 threads, 8x8 microtile, pairwise-chunked accumulation
// (per-k-tile tmp then fold) to keep summation noise ~1e-6 so top-k boundary
// ordering matches the reference.
// ---------------------------------------------------------------------------
#define BM 128
#define BN 128
#define BKK 8

__global__ __launch_bounds__(256) void encode_gemm(
    const float* __restrict__ x, const float* __restrict__ W_enc,
    const float* __restrict__ b_enc, float* __restrict__ pre) {
  __shared__ float As[BKK][BM];
  __shared__ float Bs[BKK][BN];
  const int tid = threadIdx.x;
  const int bm = blockIdx.y, bn = blockIdx.x;
  const int tx = tid & 15, ty = tid >> 4;
  const int arow = tid >> 1, acol = (tid & 1) * 4;
  const int brow = tid >> 5, bcol = (tid & 31) * 4;
  const float* xrow = x + (size_t)(bm * BM + arow) * ROWLEN;
  const float* bptr = W_enc + (size_t)brow * D_SAE + (size_t)bn * BN + bcol;

  float acc[8][8];
#pragma unroll
  for (int i = 0; i < 8; ++i)
#pragma unroll
    for (int j = 0; j < 8; ++j) acc[i][j] = 0.f;

  for (int k0 = 0; k0 < KD; k0 += BKK) {
    float4 a0 = *reinterpret_cast<const float4*>(xrow + k0 + acol);
    float4 a1 = *reinterpret_cast<const float4*>(xrow + KD + k0 + acol);
    float4 bv = *reinterpret_cast<const float4*>(bptr + (size_t)k0 * D_SAE);
    As[acol + 0][arow] = a0.x + a1.x;
    As[acol + 1][arow] = a0.y + a1.y;
    As[acol + 2][arow] = a0.z + a1.z;
    As[acol + 3][arow] = a0.w + a1.w;
    *reinterpret_cast<float4*>(&Bs[brow][bcol]) = bv;
    __syncthreads();

    float tmp[8][8];
#pragma unroll
    for (int i = 0; i < 8; ++i)
#pragma unroll
      for (int j = 0; j < 8; ++j) tmp[i][j] = 0.f;

#pragma unroll
    for (int k = 0; k < BKK; ++k) {
      float a[8], b[8];
      *reinterpret_cast<float4*>(&a[0]) = *reinterpret_cast<const float4*>(&As[k][ty * 8]);
      *reinterpret_cast<float4*>(&a[4]) = *reinterpret_cast<const float4*>(&As[k][ty * 8 + 4]);
      *reinterpret_cast<float4*>(&b[0]) = *reinterpret_cast<const float4*>(&Bs[k][tx * 8]);
      *reinterpret_cast<float4*>(&b[4]) = *reinterpret_cast<const float4*>(&Bs[k][tx * 8 + 4]);
#pragma unroll
      for (int i = 0; i < 8; ++i)
#pragma unroll
        for (int j = 0; j < 8; ++j) tmp[i][j] = fmaf(a[i], b[j], tmp[i][j]);
    }
#pragma unroll
    for (int i = 0; i < 8; ++i)
#pragma unroll
      for (int j = 0; j < 8; ++j) acc[i][j] += tmp[i][j];
    __syncthreads();
  }

  const int row0 = bm * BM + ty * 8;
  const int col0 = bn * BN + tx * 8;
#pragma unroll
  for (int j = 0; j < 8; ++j) {
    float be = b_enc[col0 + j];
#pragma unroll
    for (int i = 0; i < 8; ++i)
      pre[(size_t)(row0 + i) * D_SAE + col0 + j] = acc[i][j] + be;
  }
}

// ---------------------------------------------------------------------------
// TopK: one block (256 threads) per row; each thread holds 64 monotone-u32
// keys in registers; 64 iterations of block argmax. Tie-break = smaller index
// (matches jax.lax.top_k / stable descending sort).
// ---------------------------------------------------------------------------
__global__ __launch_bounds__(256) void topk_kernel(
    const float* __restrict__ pre, float* __restrict__ vals, int* __restrict__ idxs) {
  const int b = blockIdx.x;
  const int t = threadIdx.x;
  const float* row = pre + (size_t)b * D_SAE;

  unsigned u[64];
#pragma unroll
  for (int j = 0; j < 64; ++j) {
    unsigned bits = __float_as_uint(row[j * 256 + t]);
    // monotone map: order(u) == order(float); only negative-NaN maps to 0
    u[j] = (bits & 0x80000000u) ? ~bits : (bits | 0x80000000u);
  }

  __shared__ unsigned long long s_red[4];
  __shared__ unsigned long long s_win;
  const int wave = t >> 6, lane = t & 63;

  for (int it = 0; it < TOPK; ++it) {
    unsigned best = u[0];
    int bj = 0;
#pragma unroll
    for (int j = 1; j < 64; ++j) {
      if (u[j] > best) { best = u[j]; bj = j; }
    }
    const unsigned gidx = (unsigned)(bj * 256 + t);
    const unsigned long long mykey =
        ((unsigned long long)best << 32) | (unsigned long long)(0xFFFFFFFFu - gidx);

    unsigned long long red = mykey;
#pragma unroll
    for (int off = 32; off > 0; off >>= 1) {
      unsigned long long o = __shfl_xor(red, off, 64);
      if (o > red) red = o;
    }
    if (lane == 0) s_red[wave] = red;
    __syncthreads();
    if (t == 0) {
      unsigned long long k0 = s_red[0];
      for (int w = 1; w < 4; ++w)
        if (s_red[w] > k0) k0 = s_red[w];
      s_win = k0;
    }
    __syncthreads();
    const unsigned long long win = s_win;

    if (mykey == win) {
      // I'm the unique winner: emit and remove my element bj.
      unsigned obits = (best & 0x80000000u) ? (best ^ 0x80000000u) : ~best;
      float wval = __uint_as_float(obits);
      vals[b * TOPK + it] = fmaxf(wval, 0.f);  // relu here
      idxs[b * TOPK + it] = (int)gidx;
#pragma unroll
      for (int j = 0; j < 64; ++j)
        if (j == bj) u[j] = 0u;   // 0 == -NaN sentinel, never selected
    }
    // no trailing barrier needed: next s_win write is fenced by next barriers
  }
}

// ---------------------------------------------------------------------------
// Zero the z region of d_out (base is float-index 1+B*ROWLEN, ==1 mod 4, so
// 3 scalar head elems, float4 body, 1 tail elem).
// ---------------------------------------------------------------------------
__global__ __launch_bounds__(256) void zero_z(float* __restrict__ out) {
  float* z = out + 1 + (size_t)B_ROWS * ROWLEN;
  const size_t zlen = (size_t)B_ROWS * D_SAE;             // 67108864
  const size_t n4 = (zlen - 3) / 4;                       // body float4 count
  size_t i = (size_t)blockIdx.x * blockDim.x + threadIdx.x;
  if (i < n4) {
    reinterpret_cast<float4*>(z + 3)[i] = make_float4(0.f, 0.f, 0.f, 0.f);
  }
  if (i == 0) {
    z[0] = 0.f; z[1] = 0.f; z[2] = 0.f;
    z[zlen - 1] = 0.f;
  }
}

__global__ __launch_bounds__(256) void scatter_z(
    const float* __restrict__ vals, const int* __restrict__ idxs, float* __restrict__ out) {
  int i = blockIdx.x * blockDim.x + threadIdx.x;   // B_ROWS*TOPK threads
  int b = i >> 6;
  float* z = out + 1 + (size_t)B_ROWS * ROWLEN;
  z[(size_t)b * D_SAE + (size_t)idxs[i]] = vals[i];
}

// ---------------------------------------------------------------------------
// Decode + fused loss: one block (384 threads) per b.
// x_hat[b,e] = b_dec[e] + sum_k vals[k] * W_dec[idx[k], e];  partial[b] = ||x_hat-x||^2
// ---------------------------------------------------------------------------
__global__ __launch_bounds__(384) void decode_kernel(
    const float* __restrict__ x, const float* __restrict__ W_dec,
    const float* __restrict__ b_dec, const float* __restrict__ vals,
    const int* __restrict__ idxs, float* __restrict__ out, float* __restrict__ partial) {
  const int b = blockIdx.x, t = threadIdx.x;
  __shared__ float sv[TOPK];
  __shared__ int   si[TOPK];
  if (t < TOPK) {
    sv[t] = vals[b * TOPK + t];
    si[t] = idxs[b * TOPK + t];
  }
  __syncthreads();

  const float4* bd4 = reinterpret_cast<const float4*>(b_dec);
  float4 acc[3];
#pragma unroll
  for (int j = 0; j < 3; ++j) acc[j] = bd4[t + 384 * j];

  const float4* wd4 = reinterpret_cast<const float4*>(W_dec);
#pragma unroll 4
  for (int k = 0; k < TOPK; ++k) {
    const float v = sv[k];
    const float4* wrow = wd4 + (size_t)si[k] * (ROWLEN / 4);
#pragma unroll
    for (int j = 0; j < 3; ++j) {
      float4 w = wrow[t + 384 * j];
      acc[j].x = fmaf(v, w.x, acc[j].x);
      acc[j].y = fmaf(v, w.y, acc[j].y);
      acc[j].z = fmaf(v, w.z, acc[j].z);
      acc[j].w = fmaf(v, w.w, acc[j].w);
    }
  }

  const float4* x4 = reinterpret_cast<const float4*>(x) + (size_t)b * (ROWLEN / 4);
  float* xh = out + 1 + (size_t)b * ROWLEN;
  float s = 0.f;
#pragma unroll
  for (int j = 0; j < 3; ++j) {
    const int p = t + 384 * j;
    float4 xv = x4[p];
    float4 a = acc[j];
    xh[p * 4 + 0] = a.x;
    xh[p * 4 + 1] = a.y;
    xh[p * 4 + 2] = a.z;
    xh[p * 4 + 3] = a.w;
    float dx = a.x - xv.x; s = fmaf(dx, dx, s);
    dx = a.y - xv.y; s = fmaf(dx, dx, s);
    dx = a.z - xv.z; s = fmaf(dx, dx, s);
    dx = a.w - xv.w; s = fmaf(dx, dx, s);
  }

#pragma unroll
  for (int off = 32; off > 0; off >>= 1) s += __shfl_down(s, off, 64);
  __shared__ float sp[6];
  const int wave = t >> 6, lane = t & 63;
  if (lane == 0) sp[wave] = s;
  __syncthreads();
  if (t == 0) {
    float tot = 0.f;
#pragma unroll
    for (int w = 0; w < 6; ++w) tot += sp[w];
    partial[b] = tot;
  }
}

__global__ __launch_bounds__(256) void loss_reduce(
    const float* __restrict__ partial, float* __restrict__ out) {
  const int t = threadIdx.x;
  float s = 0.f;
  for (int i = t; i < B_ROWS; i += 256) s += partial[i];
#pragma unroll
  for (int off = 32; off > 0; off >>= 1) s += __shfl_down(s, off, 64);
  __shared__ float sp[4];
  const int wave = t >> 6, lane = t & 63;
  if (lane == 0) sp[wave] = s;
  __syncthreads();
  if (t == 0) {
    float tot = sp[0] + sp[1] + sp[2] + sp[3];
    out[0] = tot * (1.0f / 24576.0f);   // mean over B*T*L groups
  }
}

// ---------------------------------------------------------------------------
extern "C" void kernel_launch(void* const* d_in, const int* in_sizes, int n_in,
                              void* d_out, int out_size, void* d_ws, size_t ws_size,
                              hipStream_t stream) {
  const float* x     = (const float*)d_in[0];
  const float* W_enc = (const float*)d_in[1];
  const float* b_enc = (const float*)d_in[2];
  const float* W_dec = (const float*)d_in[3];
  const float* b_dec = (const float*)d_in[4];
  float* out = (float*)d_out;

  // d_out layout: [loss(1)][x_hat(B*ROWLEN)][z(B*D_SAE)]
  float* z_region = out + 1 + (size_t)B_ROWS * ROWLEN;   // pre lives here first

  int*   idxs    = (int*)d_ws;                               // B*64 ints
  float* vals    = (float*)d_ws + (size_t)B_ROWS * TOPK;     // B*64 floats
  float* partial = (float*)d_ws + (size_t)2 * B_ROWS * TOPK; // B floats

  // 1) pre = encode GEMM  (written into z region of d_out)
  encode_gemm<<<dim3(D_SAE / BN, B_ROWS / BM), 256, 0, stream>>>(x, W_enc, b_enc, z_region);
  // 2) top-64 per row -> vals (relu'd) / idxs in ws
  topk_kernel<<<B_ROWS, 256, 0, stream>>>(z_region, vals, idxs);
  // 3) zero z, 4) scatter relu(vals)
  zero_z<<<65536, 256, 0, stream>>>(out);
  scatter_z<<<(B_ROWS * TOPK) / 256, 256, 0, stream>>>(vals, idxs, out);
  // 5) decode + fused loss partials, 6) final loss reduce
  decode_kernel<<<B_ROWS, 384, 0, stream>>>(x, W_dec, b_dec, vals, idxs, out, partial);
  loss_reduce<<<1, 256, 0, stream>>>(partial, out);
}

// Round 2
// 2993.141 us; speedup vs baseline: 2.0292x; 2.0292x over previous
//
#include <hip/hip_runtime.h>
#include <cstdint>
#include <cstddef>

#define B_ROWS 4096
#define D_SAE  16384
#define KD     2304    // L*D_IN contraction length
#define ROWLEN 4608    // T*L*D_IN decode row length
#define TOPK   64
#define NKT    72      // KD/32 k-tiles
#define LO_SCALE 4096.0f
#define LO_INV  (1.0f/4096.0f)

typedef _Float16 half4v __attribute__((ext_vector_type(4)));
typedef _Float16 half8v __attribute__((ext_vector_type(8)));
typedef float floatx16 __attribute__((ext_vector_type(16)));
typedef __attribute__((address_space(1))) const uint32_t u32_g;
typedef __attribute__((address_space(3))) uint32_t u32_l;

// ---------------------------------------------------------------------------
// prep_a: xs = x[b,0,:]+x[b,1,:]; split into f16 hi plane and f16 lo plane
// (lo scaled by 2^12 so all values are f16-normal; exact power-of-2).
// Planes live in the x_hat region of d_out (overwritten later by decode).
// ---------------------------------------------------------------------------
__global__ __launch_bounds__(256) void prep_a(const float* __restrict__ x,
                                              _Float16* __restrict__ Ah,
                                              _Float16* __restrict__ Al) {
  int i = blockIdx.x * 256 + threadIdx.x;      // 4096*576 threads
  int b = i / 576;
  int c = (i % 576) * 4;
  const float* xr = x + (size_t)b * ROWLEN + c;
  float4 a0 = *(const float4*)xr;
  float4 a1 = *(const float4*)(xr + KD);
  float s[4] = {a0.x + a1.x, a0.y + a1.y, a0.z + a1.z, a0.w + a1.w};
  half4v h, l;
#pragma unroll
  for (int j = 0; j < 4; ++j) {
    _Float16 hh = (_Float16)s[j];
    h[j] = hh;
    l[j] = (_Float16)((s[j] - (float)hh) * LO_SCALE);
  }
  *(half4v*)(Ah + (size_t)b * KD + c) = h;
  *(half4v*)(Al + (size_t)b * KD + c) = l;
}

// ---------------------------------------------------------------------------
// encode_mfma: pre[128x128 tile] via v_mfma_f32_32x32x16_f16.
// pre = Ah*Bh  +  2^-12 * (Al'*Bh + Ah*Bl')   (l-planes pre-scaled by 2^12)
// LDS tiles [row][32k] f16, 16B chunks XOR-swizzled by (row>>1)&3 so the
// fragment ds_read_b128s are ~2-way (free). A staged via global_load_lds
// width=16; W converted fp32->f16 hi/lo on the fly (prefetched 1 k-tile).
// ---------------------------------------------------------------------------
__global__ __launch_bounds__(256) void encode_mfma(
    const _Float16* __restrict__ Ah, const _Float16* __restrict__ Al,
    const float* __restrict__ W, const float* __restrict__ b_enc,
    float* __restrict__ pre) {
  __shared__ _Float16 lds[4 * 4096];           // sAh | sAl | sBh | sBl (32 KB)
  _Float16* sAh = lds;
  _Float16* sAl = lds + 4096;
  _Float16* sBh = lds + 8192;
  _Float16* sBl = lds + 12288;

  const int tid = threadIdx.x;
  const int nblk = blockIdx.x, mblk = blockIdx.y;
  const int lane = tid & 63, wave = tid >> 6;
  const int wm = wave & 1, wn = wave >> 1;     // wave -> 64x64 subtile
  const int q = lane >> 5, mrow = lane & 31;

  // B staging ids: thread covers k = kg*4..+3, n = ng*4..+3 of the 32x128 W tile
  const int kg = tid & 7, ng = tid >> 3;
  const float* wcol = W + (size_t)nblk * 128 + ng * 4;

  // A staging (glds): two iters, thread -> row (it*64 + tid>>2), slot tid&3
  const int ar = tid >> 2, ac = tid & 3;
  const _Float16* gAh = Ah + (size_t)(mblk * 128) * KD;
  const _Float16* gAl = Al + (size_t)(mblk * 128) * KD;

  floatx16 acc1[2][2], acc2[2][2];
#pragma unroll
  for (int a = 0; a < 2; ++a)
#pragma unroll
    for (int b2 = 0; b2 < 2; ++b2)
#pragma unroll
      for (int e = 0; e < 16; ++e) { acc1[a][b2][e] = 0.f; acc2[a][b2][e] = 0.f; }

  // prefetch W rows for k-tile 0
  float4 wreg[4];
#pragma unroll
  for (int i = 0; i < 4; ++i)
    wreg[i] = *(const float4*)(wcol + (size_t)(kg * 4 + i) * D_SAE);

  for (int kt = 0; kt < NKT; ++kt) {
    const int k0 = kt * 32;
    __syncthreads();   // all waves done reading previous tiles

    // ---- stage A (async, width=16), swizzled chunk choice on the gather side
#pragma unroll
    for (int it = 0; it < 2; ++it) {
      int r = it * 64 + ar;
      int cg = ac ^ ((r >> 1) & 3);
      const _Float16* sa = gAh + (size_t)r * KD + k0 + cg * 8;
      const _Float16* sb = gAl + (size_t)r * KD + k0 + cg * 8;
      __builtin_amdgcn_global_load_lds((u32_g*)sa, (u32_l*)(sAh + it * 2048 + wave * 512), 16, 0, 0);
      __builtin_amdgcn_global_load_lds((u32_g*)sb, (u32_l*)(sAl + it * 2048 + wave * 512), 16, 0, 0);
    }

    // ---- stage B: convert prefetched W fp32 -> f16 hi / scaled lo, transpose to [n][k]
    const float* wf = (const float*)wreg;
#pragma unroll
    for (int j = 0; j < 4; ++j) {
      half4v h, l;
#pragma unroll
      for (int i = 0; i < 4; ++i) {
        float v = wf[i * 4 + j];
        _Float16 hh = (_Float16)v;
        h[i] = hh;
        l[i] = (_Float16)((v - (float)hh) * LO_SCALE);
      }
      int n = ng * 4 + j;
      int slot = (kg >> 1) ^ ((n >> 1) & 3);
      int off = n * 32 + slot * 8 + (kg & 1) * 4;   // halves
      *(half4v*)(sBh + off) = h;
      *(half4v*)(sBl + off) = l;
    }
    __syncthreads();   // tiles ready (compiler drains vmcnt+lgkmcnt)

    // ---- prefetch next W k-tile (overlaps MFMA)
    if (kt + 1 < NKT) {
#pragma unroll
      for (int i = 0; i < 4; ++i)
        wreg[i] = *(const float4*)(wcol + (size_t)((kt + 1) * 32 + kg * 4 + i) * D_SAE);
    }

    // ---- compute: 2 k16-halves x 2x2 subtiles x 3 terms
#pragma unroll
    for (int h = 0; h < 2; ++h) {
      const int wantc = h * 2 + q;
      half8v fah[2], fal[2], fbh[2], fbl[2];
#pragma unroll
      for (int ms = 0; ms < 2; ++ms) {
        int r = wm * 64 + ms * 32 + mrow;
        int off = r * 32 + (wantc ^ ((r >> 1) & 3)) * 8;
        fah[ms] = *(const half8v*)(sAh + off);
        fal[ms] = *(const half8v*)(sAl + off);
      }
#pragma unroll
      for (int ns = 0; ns < 2; ++ns) {
        int r = wn * 64 + ns * 32 + mrow;
        int off = r * 32 + (wantc ^ ((r >> 1) & 3)) * 8;
        fbh[ns] = *(const half8v*)(sBh + off);
        fbl[ns] = *(const half8v*)(sBl + off);
      }
#pragma unroll
      for (int ms = 0; ms < 2; ++ms)
#pragma unroll
        for (int ns = 0; ns < 2; ++ns) {
          acc1[ms][ns] = __builtin_amdgcn_mfma_f32_32x32x16_f16(fah[ms], fbh[ns], acc1[ms][ns], 0, 0, 0);
          acc2[ms][ns] = __builtin_amdgcn_mfma_f32_32x32x16_f16(fal[ms], fbh[ns], acc2[ms][ns], 0, 0, 0);
          acc2[ms][ns] = __builtin_amdgcn_mfma_f32_32x32x16_f16(fah[ms], fbl[ns], acc2[ms][ns], 0, 0, 0);
        }
    }
  }

  // ---- epilogue: C/D layout col=lane&31, row=(reg&3)+8*(reg>>2)+4*(lane>>5)
  const int col = mrow;
  const int rbase = 4 * q;
#pragma unroll
  for (int ns = 0; ns < 2; ++ns) {
    int gn = nblk * 128 + wn * 64 + ns * 32 + col;
    float be = b_enc[gn];
#pragma unroll
    for (int ms = 0; ms < 2; ++ms) {
      int gm0 = mblk * 128 + wm * 64 + ms * 32;
#pragma unroll
      for (int r = 0; r < 16; ++r) {
        int row = rbase + (r & 3) + 8 * (r >> 2);
        pre[(size_t)(gm0 + row) * D_SAE + gn] = acc1[ms][ns][r] + acc2[ms][ns][r] * LO_INV + be;
      }
    }
  }
}

// ---------------------------------------------------------------------------
// TopK: one block (256 threads) per row; 64 iterations of block argmax.
// ---------------------------------------------------------------------------
__global__ __launch_bounds__(256) void topk_kernel(
    const float* __restrict__ pre, float* __restrict__ vals, int* __restrict__ idxs) {
  const int b = blockIdx.x;
  const int t = threadIdx.x;
  const float* row = pre + (size_t)b * D_SAE;

  unsigned u[64];
#pragma unroll
  for (int j = 0; j < 64; ++j) {
    unsigned bits = __float_as_uint(row[j * 256 + t]);
    u[j] = (bits & 0x80000000u) ? ~bits : (bits | 0x80000000u);
  }

  __shared__ unsigned long long s_red[4];
  __shared__ unsigned long long s_win;
  const int wave = t >> 6, lane = t & 63;

  for (int it = 0; it < TOPK; ++it) {
    unsigned best = u[0];
    int bj = 0;
#pragma unroll
    for (int j = 1; j < 64; ++j) {
      if (u[j] > best) { best = u[j]; bj = j; }
    }
    const unsigned gidx = (unsigned)(bj * 256 + t);
    const unsigned long long mykey =
        ((unsigned long long)best << 32) | (unsigned long long)(0xFFFFFFFFu - gidx);

    unsigned long long red = mykey;
#pragma unroll
    for (int off = 32; off > 0; off >>= 1) {
      unsigned long long o = __shfl_xor(red, off, 64);
      if (o > red) red = o;
    }
    if (lane == 0) s_red[wave] = red;
    __syncthreads();
    if (t == 0) {
      unsigned long long k0 = s_red[0];
      for (int w = 1; w < 4; ++w)
        if (s_red[w] > k0) k0 = s_red[w];
      s_win = k0;
    }
    __syncthreads();
    const unsigned long long win = s_win;

    if (mykey == win) {
      unsigned obits = (best & 0x80000000u) ? (best ^ 0x80000000u) : ~best;
      float wval = __uint_as_float(obits);
      vals[b * TOPK + it] = fmaxf(wval, 0.f);
      idxs[b * TOPK + it] = (int)gidx;
#pragma unroll
      for (int j = 0; j < 64; ++j)
        if (j == bj) u[j] = 0u;
    }
  }
}

// ---------------------------------------------------------------------------
__global__ __launch_bounds__(256) void zero_z(float* __restrict__ out) {
  float* z = out + 1 + (size_t)B_ROWS * ROWLEN;
  const size_t zlen = (size_t)B_ROWS * D_SAE;
  const size_t n4 = (zlen - 3) / 4;
  size_t i = (size_t)blockIdx.x * blockDim.x + threadIdx.x;
  if (i < n4) {
    reinterpret_cast<float4*>(z + 3)[i] = make_float4(0.f, 0.f, 0.f, 0.f);
  }
  if (i == 0) {
    z[0] = 0.f; z[1] = 0.f; z[2] = 0.f;
    z[zlen - 1] = 0.f;
  }
}

__global__ __launch_bounds__(256) void scatter_z(
    const float* __restrict__ vals, const int* __restrict__ idxs, float* __restrict__ out) {
  int i = blockIdx.x * blockDim.x + threadIdx.x;
  int b = i >> 6;
  float* z = out + 1 + (size_t)B_ROWS * ROWLEN;
  z[(size_t)b * D_SAE + (size_t)idxs[i]] = vals[i];
}

// ---------------------------------------------------------------------------
__global__ __launch_bounds__(384) void decode_kernel(
    const float* __restrict__ x, const float* __restrict__ W_dec,
    const float* __restrict__ b_dec, const float* __restrict__ vals,
    const int* __restrict__ idxs, float* __restrict__ out, float* __restrict__ partial) {
  const int b = blockIdx.x, t = threadIdx.x;
  __shared__ float sv[TOPK];
  __shared__ int   si[TOPK];
  if (t < TOPK) {
    sv[t] = vals[b * TOPK + t];
    si[t] = idxs[b * TOPK + t];
  }
  __syncthreads();

  const float4* bd4 = reinterpret_cast<const float4*>(b_dec);
  float4 acc[3];
#pragma unroll
  for (int j = 0; j < 3; ++j) acc[j] = bd4[t + 384 * j];

  const float4* wd4 = reinterpret_cast<const float4*>(W_dec);
#pragma unroll 4
  for (int k = 0; k < TOPK; ++k) {
    const float v = sv[k];
    const float4* wrow = wd4 + (size_t)si[k] * (ROWLEN / 4);
#pragma unroll
    for (int j = 0; j < 3; ++j) {
      float4 w = wrow[t + 384 * j];
      acc[j].x = fmaf(v, w.x, acc[j].x);
      acc[j].y = fmaf(v, w.y, acc[j].y);
      acc[j].z = fmaf(v, w.z, acc[j].z);
      acc[j].w = fmaf(v, w.w, acc[j].w);
    }
  }

  const float4* x4 = reinterpret_cast<const float4*>(x) + (size_t)b * (ROWLEN / 4);
  float* xh = out + 1 + (size_t)b * ROWLEN;
  float s = 0.f;
#pragma unroll
  for (int j = 0; j < 3; ++j) {
    const int p = t + 384 * j;
    float4 xv = x4[p];
    float4 a = acc[j];
    xh[p * 4 + 0] = a.x;
    xh[p * 4 + 1] = a.y;
    xh[p * 4 + 2] = a.z;
    xh[p * 4 + 3] = a.w;
    float dx = a.x - xv.x; s = fmaf(dx, dx, s);
    dx = a.y - xv.y; s = fmaf(dx, dx, s);
    dx = a.z - xv.z; s = fmaf(dx, dx, s);
    dx = a.w - xv.w; s = fmaf(dx, dx, s);
  }

#pragma unroll
  for (int off = 32; off > 0; off >>= 1) s += __shfl_down(s, off, 64);
  __shared__ float sp[6];
  const int wave = t >> 6, lane = t & 63;
  if (lane == 0) sp[wave] = s;
  __syncthreads();
  if (t == 0) {
    float tot = 0.f;
#pragma unroll
    for (int w = 0; w < 6; ++w) tot += sp[w];
    partial[b] = tot;
  }
}

__global__ __launch_bounds__(256) void loss_reduce(
    const float* __restrict__ partial, float* __restrict__ out) {
  const int t = threadIdx.x;
  float s = 0.f;
  for (int i = t; i < B_ROWS; i += 256) s += partial[i];
#pragma unroll
  for (int off = 32; off > 0; off >>= 1) s += __shfl_down(s, off, 64);
  __shared__ float sp[4];
  const int wave = t >> 6, lane = t & 63;
  if (lane == 0) sp[wave] = s;
  __syncthreads();
  if (t == 0) {
    float tot = sp[0] + sp[1] + sp[2] + sp[3];
    out[0] = tot * (1.0f / 24576.0f);
  }
}

// ---------------------------------------------------------------------------
extern "C" void kernel_launch(void* const* d_in, const int* in_sizes, int n_in,
                              void* d_out, int out_size, void* d_ws, size_t ws_size,
                              hipStream_t stream) {
  const float* x     = (const float*)d_in[0];
  const float* W_enc = (const float*)d_in[1];
  const float* b_enc = (const float*)d_in[2];
  const float* W_dec = (const float*)d_in[3];
  const float* b_dec = (const float*)d_in[4];
  float* out = (float*)d_out;

  // d_out layout: [loss(1)][x_hat(B*ROWLEN)][z(B*D_SAE)]
  float* z_region = out + 1 + (size_t)B_ROWS * ROWLEN;   // pre lives here first

  // f16 A planes parked in the x_hat region (out+8 -> 32B aligned; decode
  // overwrites this region only after the GEMM has consumed it)
  _Float16* Ah = (_Float16*)(out + 8);
  _Float16* Al = Ah + (size_t)B_ROWS * KD;

  int*   idxs    = (int*)d_ws;                               // B*64 ints
  float* vals    = (float*)d_ws + (size_t)B_ROWS * TOPK;     // B*64 floats
  float* partial = (float*)d_ws + (size_t)2 * B_ROWS * TOPK; // B floats

  prep_a<<<9216, 256, 0, stream>>>(x, Ah, Al);
  encode_mfma<<<dim3(D_SAE / 128, B_ROWS / 128), 256, 0, stream>>>(Ah, Al, W_enc, b_enc, z_region);
  topk_kernel<<<B_ROWS, 256, 0, stream>>>(z_region, vals, idxs);
  zero_z<<<65536, 256, 0, stream>>>(out);
  scatter_z<<<(B_ROWS * TOPK) / 256, 256, 0, stream>>>(vals, idxs, out);
  decode_kernel<<<B_ROWS, 384, 0, stream>>>(x, W_dec, b_dec, vals, idxs, out, partial);
  loss_reduce<<<1, 256, 0, stream>>>(partial, out);
}